// Round 16
// baseline (117.996 us; speedup 1.0000x reference)
//
#include <hip/hip_runtime.h>
#include <hip/hip_bf16.h>

// LearnableVQ forward on MI355X — v13: r14 VERBATIM (2x3 split MFMA chains,
// int-key fold, 1-barrier dbuf, gated f64 refine, coalesced stores) with ONLY
// depth-2 register prefetch added (isolating r15's confounded A/B: the
// single-chain acc was the regression; prefetch depth is tested alone here).
// B=8 H=8 L=4096 DK=64 S=512. Inputs f32; output f32:
//   vecs_hat[B,H,L,DK] | z[B,H,L] | l_commit | l_codebook | errs2[B,H,L]
// Codebook split + A-frags pre-scaled by 16 (bf16-exact) -> MFMA = 256*dot.
// INIT = fmaf(-128, c2, 65536) -> m' in [~28k, ~87k] > 0.
// FOLD: ki=(int)(cA+cB); key=(ki<<9)+(511-code); quantum 1/256 (r14-proven).

#define Bc 8
#define Hc 8
#define Lc 4096
#define DKc 64
#define Sc 512

typedef __attribute__((ext_vector_type(8))) short bf16x8;
typedef __attribute__((ext_vector_type(8))) unsigned short u16x8;
typedef __attribute__((ext_vector_type(4))) float f32x4;

// ---------------- ws layout (bytes) ----------------
#define WS_C_OFF    0u          // H*S*DK f32           = 1,048,576
#define WS_C2_OFF   1048576u    // H*S f32              =    16,384
#define WS_CBH_OFF  1064960u    // H*S*DK bf16 hi x16 (swz) = 524,288
#define WS_CBL_OFF  1589248u    // H*S*DK bf16 lo x16 (swz) = 524,288
#define WS_PART_OFF 2113536u    // 8192 f32             =    32,768
#define NPART       8192

__device__ __forceinline__ unsigned short f32_to_bf16_rne(float x) {
    unsigned u = __float_as_uint(x);
    unsigned r = (u + 0x7FFFu + ((u >> 16) & 1u)) >> 16;
    return (unsigned short)r;
}
__device__ __forceinline__ float bf16_hi_f32(unsigned short h) {
    return __uint_as_float(((unsigned)h) << 16);
}

// ---------------- prep: normalize codebook; c2; pre-split (x16) pre-swizzled bf16 ----------------
__global__ __launch_bounds__(256) void prep_kernel(
        const float* __restrict__ c_sum,
        const float* __restrict__ c_count,
        float* __restrict__ c,
        float* __restrict__ c2,
        unsigned short* __restrict__ cbh,
        unsigned short* __restrict__ cbl) {
    int row  = (blockIdx.x * blockDim.x + threadIdx.x) >> 6;   // h*512 + s
    int lane = threadIdx.x & 63;
    float cnt = c_count[row];
    float inv = 1.0f / fmaxf(cnt, 0.01f);
    float val = c_sum[row * DKc + lane] * inv;
    c[row * DKc + lane] = val;
    float v16 = val * 16.0f;                                   // exact scale
    unsigned short hi = f32_to_bf16_rne(v16);
    unsigned short lo = f32_to_bf16_rne(v16 - bf16_hi_f32(hi));
    int s = row & (Sc - 1);
    size_t hbase = (size_t)(row >> 9) * (Sc * 128);            // bytes per head
    int boff = (s * 128 + lane * 2) ^ ((s & 7) << 4);          // swizzled layout
    *(unsigned short*)((char*)cbh + hbase + boff) = hi;
    *(unsigned short*)((char*)cbl + hbase + boff) = lo;
    float sq = val * val;                                      // unscaled c2
    #pragma unroll
    for (int off = 32; off; off >>= 1) sq += __shfl_xor(sq, off);
    if (lane == 0) c2[row] = sq;
}

// ---------------- fused kernel: 4 waves, 128 rows, dbuf 32-code chunks ----------------
__global__ __launch_bounds__(256, 4) void vq_mfma_kernel(
        const float* __restrict__ vecs,
        const float* __restrict__ c,
        const float* __restrict__ c2,
        const unsigned short* __restrict__ cbh,
        const unsigned short* __restrict__ cbl,
        const float* __restrict__ loss_mask,
        float* __restrict__ out_vh,
        float* __restrict__ out_z,
        float* __restrict__ out_err,
        float* __restrict__ partials) {
    __shared__ unsigned short bhi[2][32 * DKc];   // 2 x 4 KiB (swizzled content)
    __shared__ unsigned short blo[2][32 * DKc];   // 2 x 4 KiB
    __shared__ float c2_lds[Sc];                  // 2 KiB
    __shared__ int2  top2s[128];                  // 1 KiB -> 19.4 KiB total

    const int t   = threadIdx.x;
    const int l   = t & 63;
    const int w   = t >> 6;
    const int col = l & 15;
    const int ksl = l >> 4;

    // XCD head-affinity: consecutive-8 blocks round-robin XCDs; XCD i -> head i.
    const int flat = blockIdx.x;        // 0..2047
    const int h    = flat & 7;
    const int idx  = flat >> 3;         // 0..255
    const int b    = idx >> 5;
    const int lt   = idx & 31;          // 128-row tile
    const int bh   = b * Hc + h;

    const float* Avec  = vecs + ((size_t)bh * Lc + (size_t)lt * 128) * DKc;
    const float* Bp    = c + (size_t)h * Sc * DKc;
    const char*  cbh_h = (const char*)cbh + (size_t)h * (Sc * 128);
    const char*  cbl_h = (const char*)cbl + (size_t)h * (Sc * 128);

    // ---- depth-2 prefetch register sets: L_k -> set[k&1] ----
    u16x8 nh0, nl0, nh1, nl1;
    // issue L0 -> set0 (returns under A-convert)
    nh0 = *(const u16x8*)(cbh_h + w * 1024 + l * 16);
    nl0 = *(const u16x8*)(cbl_h + w * 1024 + l * 16);

    // ---- A fragments: rows w*32 + rt*16 + col; bf16 hi/lo (x16 scale) in-reg ----
    bf16x8 fah[2][2], fal[2][2];
    #pragma unroll
    for (int rt = 0; rt < 2; ++rt) {
        const float* Ar = Avec + (size_t)((w << 5) + (rt << 4) + col) * DKc;
        #pragma unroll
        for (int ks = 0; ks < 2; ++ks) {
            int k0 = (ks << 5) + (ksl << 3);
            float4 p0 = *reinterpret_cast<const float4*>(Ar + k0);
            float4 p1 = *reinterpret_cast<const float4*>(Ar + k0 + 4);
            float e8[8] = {p0.x, p0.y, p0.z, p0.w, p1.x, p1.y, p1.z, p1.w};
            bf16x8 hv, lv;
            #pragma unroll
            for (int i = 0; i < 8; ++i) {
                float v16 = e8[i] * 16.0f;                     // exact scale
                unsigned short hi = f32_to_bf16_rne(v16);
                hv[i] = (short)hi;
                lv[i] = (short)f32_to_bf16_rne(v16 - bf16_hi_f32(hi));
            }
            fah[rt][ks] = hv;
            fal[rt][ks] = lv;
        }
    }

    c2_lds[t]       = c2[h * Sc + t];
    c2_lds[t + 256] = c2[h * Sc + t + 256];

    // ---- write chunk 0 (set0) into buffer 0; issue L1 -> set1 ----
    *(u16x8*)((char*)bhi[0] + w * 1024 + l * 16) = nh0;
    *(u16x8*)((char*)blo[0] + w * 1024 + l * 16) = nl0;
    nh1 = *(const u16x8*)(cbh_h + (1 << 12) + w * 1024 + l * 16);
    nl1 = *(const u16x8*)(cbl_h + (1 << 12) + w * 1024 + l * 16);
    __syncthreads();

    // per-lane top-2 over integer keys: key = ((int)m' << 9) + (511 - code)
    unsigned v1k[2][4], v2k[2][4];
    #pragma unroll
    for (int rt = 0; rt < 2; ++rt)
        #pragma unroll
        for (int r = 0; r < 4; ++r) { v1k[rt][r] = 0u; v2k[rt][r] = 0u; }

    for (int chunk = 0; chunk < 16; ++chunk) {
        // depth-2: issue L(chunk+2) into the set freed at end of chunk-1
        if (chunk < 14) {
            if ((chunk & 1) == 0) {
                nh0 = *(const u16x8*)(cbh_h + ((chunk + 2) << 12) + w * 1024 + l * 16);
                nl0 = *(const u16x8*)(cbl_h + ((chunk + 2) << 12) + w * 1024 + l * 16);
            } else {
                nh1 = *(const u16x8*)(cbh_h + ((chunk + 2) << 12) + w * 1024 + l * 16);
                nl1 = *(const u16x8*)(cbl_h + ((chunk + 2) << 12) + w * 1024 + l * 16);
            }
        }
        const char* ph = (const char*)bhi[chunk & 1];
        const char* pl = (const char*)blo[chunk & 1];

        auto INIT = [&](int j, f32x4 (&cA)[2], f32x4 (&cB)[2]) {
            // m' = 65536 + 256*dot - 128*c2  (positive, < 2^17)
            float m0 = fmaf(-128.0f, c2_lds[(chunk << 5) + (j << 4) + col], 65536.0f);
            cA[0] = (f32x4){m0, m0, m0, m0};
            cA[1] = (f32x4){m0, m0, m0, m0};
            cB[0] = (f32x4){0.f, 0.f, 0.f, 0.f};
            cB[1] = (f32x4){0.f, 0.f, 0.f, 0.f};
        };
        auto STEP = [&](int j, f32x4 (&cA)[2], f32x4 (&cB)[2]) {
            int crow = (j << 4) + col;
            int o0 = ((crow << 7) + (ksl << 4)) ^ ((col & 7) << 4);
            bf16x8 h0 = *reinterpret_cast<const bf16x8*>(ph + o0);
            bf16x8 h1 = *reinterpret_cast<const bf16x8*>(ph + (o0 ^ 64));
            bf16x8 g0 = *reinterpret_cast<const bf16x8*>(pl + o0);
            bf16x8 g1 = *reinterpret_cast<const bf16x8*>(pl + (o0 ^ 64));
            #pragma unroll
            for (int rt = 0; rt < 2; ++rt) {
                cA[rt] = __builtin_amdgcn_mfma_f32_16x16x32_bf16(fah[rt][0], h0, cA[rt], 0, 0, 0);
                cB[rt] = __builtin_amdgcn_mfma_f32_16x16x32_bf16(fal[rt][0], h0, cB[rt], 0, 0, 0);
                cA[rt] = __builtin_amdgcn_mfma_f32_16x16x32_bf16(fah[rt][1], h1, cA[rt], 0, 0, 0);
                cB[rt] = __builtin_amdgcn_mfma_f32_16x16x32_bf16(fal[rt][1], h1, cB[rt], 0, 0, 0);
                cA[rt] = __builtin_amdgcn_mfma_f32_16x16x32_bf16(fah[rt][0], g0, cA[rt], 0, 0, 0);
                cB[rt] = __builtin_amdgcn_mfma_f32_16x16x32_bf16(fah[rt][1], g1, cB[rt], 0, 0, 0);
            }
        };
        auto FOLD = [&](int j, f32x4 (&cA)[2], f32x4 (&cB)[2]) {
            unsigned invc = 511u - (unsigned)((chunk << 5) + (j << 4) + col);
            #pragma unroll
            for (int rt = 0; rt < 2; ++rt)
                #pragma unroll
                for (int r = 0; r < 4; ++r) {
                    float m = cA[rt][r] + cB[rt][r];           // positive
                    unsigned ki  = (unsigned)(int)m;           // floor, monotone
                    unsigned key = (ki << 9) + invc;           // lshl_add
                    unsigned a = key > v2k[rt][r] ? key : v2k[rt][r];
                    v2k[rt][r] = a < v1k[rt][r] ? a : v1k[rt][r];
                    v1k[rt][r] = key > v1k[rt][r] ? key : v1k[rt][r];
                }
        };

        // 2 tiles per chunk, 2-slot rotation
        f32x4 sA0[2], sB0[2], sA1[2], sB1[2];
        INIT(0, sA0, sB0); STEP(0, sA0, sB0);
        INIT(1, sA1, sB1); STEP(1, sA1, sB1);
        FOLD(0, sA0, sB0);
        FOLD(1, sA1, sB1);

        if (chunk < 15) {
            // write L(chunk+1) (held in set[(chunk+1)&1]) into the idle buffer;
            // all reads of that buffer completed before the previous barrier.
            if (((chunk + 1) & 1) == 0) {
                *(u16x8*)((char*)bhi[0] + w * 1024 + l * 16) = nh0;
                *(u16x8*)((char*)blo[0] + w * 1024 + l * 16) = nl0;
            } else {
                *(u16x8*)((char*)bhi[1] + w * 1024 + l * 16) = nh1;
                *(u16x8*)((char*)blo[1] + w * 1024 + l * 16) = nl1;
            }
            __syncthreads();
        }
    }

    // ---- cross-lane top-2 merge over the 16 cols sharing each row (keys) ----
    #pragma unroll
    for (int off = 1; off <= 8; off <<= 1) {
        #pragma unroll
        for (int rt = 0; rt < 2; ++rt)
            #pragma unroll
            for (int r = 0; r < 4; ++r) {
                unsigned o1 = (unsigned)__shfl_xor((int)v1k[rt][r], off);
                unsigned o2 = (unsigned)__shfl_xor((int)v2k[rt][r], off);
                unsigned lo = min(v1k[rt][r], o1);
                v1k[rt][r]  = max(v1k[rt][r], o1);
                v2k[rt][r]  = max(lo, max(v2k[rt][r], o2));
            }
    }
    if (col == 0) {
        #pragma unroll
        for (int rt = 0; rt < 2; ++rt)
            #pragma unroll
            for (int r = 0; r < 4; ++r) {
                unsigned k1 = v1k[rt][r], k2 = v2k[rt][r];
                int z1 = 511 - (int)(k1 & 0x1FFu);
                int z2 = 511 - (int)(k2 & 0x1FFu);
                // integer gate: gap < 13/256 ~ 0.051 >> split ~1e-3 + quantum 0.0039
                bool need = ((k1 >> 9) - (k2 >> 9)) < 13u;
                top2s[(w << 5) + (rt << 4) + (ksl << 2) + r] = make_int2(z1, need ? z2 : z1);
            }
    }
    __syncthreads();

    // ---- refine: 16 lanes/row, 4 rows/iter (1KB contiguous stores);
    //      f64 delta only when top-2 genuinely close ----
    const int qo = (l & 15) << 2;       // float offset within row
    const int rq = l >> 4;              // row within 4-row group
    double macc = 0.0;
    #pragma unroll
    for (int it = 0; it < 8; ++it) {
        int  rloc = (w << 5) + (it << 2) + rq;      // block-local row 0..127
        int  lrow = lt * 128 + rloc;
        long grow = (long)bh * Lc + lrow;
        int2 zz   = top2s[rloc];
        const float* Ar = Avec + (size_t)rloc * DKc;
        const float* C1 = Bp + (size_t)zz.x * DKc;
        const float* C2 = Bp + (size_t)zz.y * DKc;
        f32x4 va = *reinterpret_cast<const f32x4*>(Ar + qo);
        f32x4 ca = *reinterpret_cast<const f32x4*>(C1 + qo);
        f32x4 cb = *reinterpret_cast<const f32x4*>(C2 + qo);
        double dd = 0.0;                // d1 - d2 = sum (c1-c2)*((c1+c2) - 2v)
        if (zz.x != zz.y) {             // uniform across the row's 16 lanes
            #pragma unroll
            for (int m = 0; m < 4; ++m) {
                double a = (double)ca[m], bb = (double)cb[m], vv = (double)va[m];
                dd = fma(a - bb, (a + bb) - 2.0 * vv, dd);
            }
            dd += __shfl_xor(dd, 1);
            dd += __shfl_xor(dd, 2);
            dd += __shfl_xor(dd, 4);
            dd += __shfl_xor(dd, 8);
        }
        bool second = (dd > 0.0) || (dd == 0.0 && zz.y < zz.x);
        int zsel = second ? zz.y : zz.x;
        f32x4 cs = second ? cb : ca;
        float e = 0.f;
        #pragma unroll
        for (int m = 0; m < 4; ++m) {
            float td = va[m] - cs[m];
            e = fmaf(td, td, e);
        }
        e += __shfl_xor(e, 1);
        e += __shfl_xor(e, 2);
        e += __shfl_xor(e, 4);
        e += __shfl_xor(e, 8);
        *reinterpret_cast<f32x4*>(out_vh + (size_t)grow * DKc + qo) = cs;
        if ((l & 15) == 0) {
            out_z[grow]   = (float)zsel;
            out_err[grow] = e;
            macc += (double)loss_mask[b * Lc + lrow] * (double)e;
        }
    }
    macc += __shfl_xor(macc, 16);
    macc += __shfl_xor(macc, 32);
    if (l == 0) partials[flat * 4 + w] = (float)macc;
}

// ---------------- finalize ----------------
__global__ __launch_bounds__(256) void finalize_kernel(
        const float* __restrict__ partials, int n,
        float* __restrict__ out_lcommit, float* __restrict__ out_lcode) {
    __shared__ double sh[256];
    double a = 0.0;
    for (int i = threadIdx.x; i < n; i += 256) a += (double)partials[i];
    sh[threadIdx.x] = a;
    __syncthreads();
    for (int s = 128; s; s >>= 1) {
        if (threadIdx.x < s) sh[threadIdx.x] += sh[threadIdx.x + s];
        __syncthreads();
    }
    if (threadIdx.x == 0) {
        double lc = sh[0] / (double)(Bc * Lc);
        *out_lcommit = (float)lc;
        *out_lcode   = 0.0f;
    }
}

extern "C" void kernel_launch(void* const* d_in, const int* in_sizes, int n_in,
                              void* d_out, int out_size, void* d_ws, size_t ws_size,
                              hipStream_t stream) {
    const float* vecs      = (const float*)d_in[0];
    const float* c_sum     = (const float*)d_in[1];
    const float* c_count   = (const float*)d_in[2];
    const float* loss_mask = (const float*)d_in[3];
    (void)in_sizes; (void)n_in; (void)out_size; (void)ws_size;

    char* ws = (char*)d_ws;
    float*          c        = (float*)(ws + WS_C_OFF);
    float*          c2       = (float*)(ws + WS_C2_OFF);
    unsigned short* cbh      = (unsigned short*)(ws + WS_CBH_OFF);
    unsigned short* cbl      = (unsigned short*)(ws + WS_CBL_OFF);
    float*          partials = (float*)(ws + WS_PART_OFF);

    float* out = (float*)d_out;
    float* out_vh      = out;                                   // B*H*L*DK
    float* out_z       = out + (size_t)Bc * Hc * Lc * DKc;      // B*H*L
    float* out_lcommit = out_z + (size_t)Bc * Hc * Lc;          // 1
    float* out_lcode   = out_lcommit + 1;                       // 1
    float* out_err     = out_lcode + 1;                         // B*H*L

    prep_kernel<<<(Hc * Sc * 64) / 256, 256, 0, stream>>>(c_sum, c_count, c, c2, cbh, cbl);

    vq_mfma_kernel<<<2048, 256, 0, stream>>>(vecs, c, c2, cbh, cbl, loss_mask,
                                             out_vh, out_z, out_err, partials);

    finalize_kernel<<<1, 256, 0, stream>>>(partials, NPART, out_lcommit, out_lcode);
}

// Round 17
// 89.231 us; speedup vs baseline: 1.3224x; 1.3224x over previous
//
#include <hip/hip_runtime.h>
#include <hip/hip_bf16.h>

// LearnableVQ forward on MI355X — FINAL: r14 verbatim (best measured: 89.4 us).
// A/B matrix r14/r15/r16 proved: 2x3 split MFMA chains + depth-1 prefetch is
// the register-budget pareto knee (depth-2 spills with split chains; single
// chain exposes MFMA dependency latency).
// B=8 H=8 L=4096 DK=64 S=512. Inputs f32; output f32:
//   vecs_hat[B,H,L,DK] | z[B,H,L] | l_commit | l_codebook | errs2[B,H,L]
// Codebook split + A-frags pre-scaled by 16 (bf16-exact) -> MFMA = 256*dot.
// INIT = fmaf(-128, c2, 65536) -> m' in [~28k, ~87k] > 0.
// FOLD: ki=(int)(cA+cB); key=(ki<<9)+(511-code); quantum 1/256; gated f64
// refine arbitrates any pair closer than 13/256 (~0.051).

#define Bc 8
#define Hc 8
#define Lc 4096
#define DKc 64
#define Sc 512

typedef __attribute__((ext_vector_type(8))) short bf16x8;
typedef __attribute__((ext_vector_type(8))) unsigned short u16x8;
typedef __attribute__((ext_vector_type(4))) float f32x4;

// ---------------- ws layout (bytes) ----------------
#define WS_C_OFF    0u          // H*S*DK f32           = 1,048,576
#define WS_C2_OFF   1048576u    // H*S f32              =    16,384
#define WS_CBH_OFF  1064960u    // H*S*DK bf16 hi x16 (swz) = 524,288
#define WS_CBL_OFF  1589248u    // H*S*DK bf16 lo x16 (swz) = 524,288
#define WS_PART_OFF 2113536u    // 8192 f32             =    32,768
#define NPART       8192

__device__ __forceinline__ unsigned short f32_to_bf16_rne(float x) {
    unsigned u = __float_as_uint(x);
    unsigned r = (u + 0x7FFFu + ((u >> 16) & 1u)) >> 16;
    return (unsigned short)r;
}
__device__ __forceinline__ float bf16_hi_f32(unsigned short h) {
    return __uint_as_float(((unsigned)h) << 16);
}

// ---------------- prep: normalize codebook; c2; pre-split (x16) pre-swizzled bf16 ----------------
__global__ __launch_bounds__(256) void prep_kernel(
        const float* __restrict__ c_sum,
        const float* __restrict__ c_count,
        float* __restrict__ c,
        float* __restrict__ c2,
        unsigned short* __restrict__ cbh,
        unsigned short* __restrict__ cbl) {
    int row  = (blockIdx.x * blockDim.x + threadIdx.x) >> 6;   // h*512 + s
    int lane = threadIdx.x & 63;
    float cnt = c_count[row];
    float inv = 1.0f / fmaxf(cnt, 0.01f);
    float val = c_sum[row * DKc + lane] * inv;
    c[row * DKc + lane] = val;
    float v16 = val * 16.0f;                                   // exact scale
    unsigned short hi = f32_to_bf16_rne(v16);
    unsigned short lo = f32_to_bf16_rne(v16 - bf16_hi_f32(hi));
    int s = row & (Sc - 1);
    size_t hbase = (size_t)(row >> 9) * (Sc * 128);            // bytes per head
    int boff = (s * 128 + lane * 2) ^ ((s & 7) << 4);          // swizzled layout
    *(unsigned short*)((char*)cbh + hbase + boff) = hi;
    *(unsigned short*)((char*)cbl + hbase + boff) = lo;
    float sq = val * val;                                      // unscaled c2
    #pragma unroll
    for (int off = 32; off; off >>= 1) sq += __shfl_xor(sq, off);
    if (lane == 0) c2[row] = sq;
}

// ---------------- fused kernel: 4 waves, 128 rows, dbuf 32-code chunks ----------------
__global__ __launch_bounds__(256, 4) void vq_mfma_kernel(
        const float* __restrict__ vecs,
        const float* __restrict__ c,
        const float* __restrict__ c2,
        const unsigned short* __restrict__ cbh,
        const unsigned short* __restrict__ cbl,
        const float* __restrict__ loss_mask,
        float* __restrict__ out_vh,
        float* __restrict__ out_z,
        float* __restrict__ out_err,
        float* __restrict__ partials) {
    __shared__ unsigned short bhi[2][32 * DKc];   // 2 x 4 KiB (swizzled content)
    __shared__ unsigned short blo[2][32 * DKc];   // 2 x 4 KiB
    __shared__ float c2_lds[Sc];                  // 2 KiB
    __shared__ int2  top2s[128];                  // 1 KiB -> 19.4 KiB total

    const int t   = threadIdx.x;
    const int l   = t & 63;
    const int w   = t >> 6;
    const int col = l & 15;
    const int ksl = l >> 4;

    // XCD head-affinity: consecutive-8 blocks round-robin XCDs; XCD i -> head i.
    const int flat = blockIdx.x;        // 0..2047
    const int h    = flat & 7;
    const int idx  = flat >> 3;         // 0..255
    const int b    = idx >> 5;
    const int lt   = idx & 31;          // 128-row tile
    const int bh   = b * Hc + h;

    const float* Avec  = vecs + ((size_t)bh * Lc + (size_t)lt * 128) * DKc;
    const float* Bp    = c + (size_t)h * Sc * DKc;
    const char*  cbh_h = (const char*)cbh + (size_t)h * (Sc * 128);
    const char*  cbl_h = (const char*)cbl + (size_t)h * (Sc * 128);

    // ---- issue chunk-0 staging loads (return under A-convert) ----
    u16x8 nh, nl;
    {
        nh = *(const u16x8*)(cbh_h + w * 1024 + l * 16);
        nl = *(const u16x8*)(cbl_h + w * 1024 + l * 16);
    }

    // ---- A fragments: rows w*32 + rt*16 + col; bf16 hi/lo (x16 scale) in-reg ----
    bf16x8 fah[2][2], fal[2][2];
    #pragma unroll
    for (int rt = 0; rt < 2; ++rt) {
        const float* Ar = Avec + (size_t)((w << 5) + (rt << 4) + col) * DKc;
        #pragma unroll
        for (int ks = 0; ks < 2; ++ks) {
            int k0 = (ks << 5) + (ksl << 3);
            float4 p0 = *reinterpret_cast<const float4*>(Ar + k0);
            float4 p1 = *reinterpret_cast<const float4*>(Ar + k0 + 4);
            float e8[8] = {p0.x, p0.y, p0.z, p0.w, p1.x, p1.y, p1.z, p1.w};
            bf16x8 hv, lv;
            #pragma unroll
            for (int i = 0; i < 8; ++i) {
                float v16 = e8[i] * 16.0f;                     // exact scale
                unsigned short hi = f32_to_bf16_rne(v16);
                hv[i] = (short)hi;
                lv[i] = (short)f32_to_bf16_rne(v16 - bf16_hi_f32(hi));
            }
            fah[rt][ks] = hv;
            fal[rt][ks] = lv;
        }
    }

    c2_lds[t]       = c2[h * Sc + t];
    c2_lds[t + 256] = c2[h * Sc + t + 256];

    // ---- write chunk 0 into buffer 0 ----
    *(u16x8*)((char*)bhi[0] + w * 1024 + l * 16) = nh;
    *(u16x8*)((char*)blo[0] + w * 1024 + l * 16) = nl;
    __syncthreads();

    // per-lane top-2 over integer keys: key = ((int)m' << 9) + (511 - code)
    unsigned v1k[2][4], v2k[2][4];
    #pragma unroll
    for (int rt = 0; rt < 2; ++rt)
        #pragma unroll
        for (int r = 0; r < 4; ++r) { v1k[rt][r] = 0u; v2k[rt][r] = 0u; }

    for (int chunk = 0; chunk < 16; ++chunk) {
        // T14: issue next chunk's loads now; written to the idle buffer at chunk end
        if (chunk < 15) {
            nh = *(const u16x8*)(cbh_h + ((chunk + 1) << 12) + w * 1024 + l * 16);
            nl = *(const u16x8*)(cbl_h + ((chunk + 1) << 12) + w * 1024 + l * 16);
        }
        const char* ph = (const char*)bhi[chunk & 1];
        const char* pl = (const char*)blo[chunk & 1];

        auto INIT = [&](int j, f32x4 (&cA)[2], f32x4 (&cB)[2]) {
            // m' = 65536 + 256*dot - 128*c2  (positive, < 2^17)
            float m0 = fmaf(-128.0f, c2_lds[(chunk << 5) + (j << 4) + col], 65536.0f);
            cA[0] = (f32x4){m0, m0, m0, m0};
            cA[1] = (f32x4){m0, m0, m0, m0};
            cB[0] = (f32x4){0.f, 0.f, 0.f, 0.f};
            cB[1] = (f32x4){0.f, 0.f, 0.f, 0.f};
        };
        auto STEP = [&](int j, f32x4 (&cA)[2], f32x4 (&cB)[2]) {
            int crow = (j << 4) + col;
            int o0 = ((crow << 7) + (ksl << 4)) ^ ((col & 7) << 4);
            bf16x8 h0 = *reinterpret_cast<const bf16x8*>(ph + o0);
            bf16x8 h1 = *reinterpret_cast<const bf16x8*>(ph + (o0 ^ 64));
            bf16x8 g0 = *reinterpret_cast<const bf16x8*>(pl + o0);
            bf16x8 g1 = *reinterpret_cast<const bf16x8*>(pl + (o0 ^ 64));
            #pragma unroll
            for (int rt = 0; rt < 2; ++rt) {
                cA[rt] = __builtin_amdgcn_mfma_f32_16x16x32_bf16(fah[rt][0], h0, cA[rt], 0, 0, 0);
                cB[rt] = __builtin_amdgcn_mfma_f32_16x16x32_bf16(fal[rt][0], h0, cB[rt], 0, 0, 0);
                cA[rt] = __builtin_amdgcn_mfma_f32_16x16x32_bf16(fah[rt][1], h1, cA[rt], 0, 0, 0);
                cB[rt] = __builtin_amdgcn_mfma_f32_16x16x32_bf16(fal[rt][1], h1, cB[rt], 0, 0, 0);
                cA[rt] = __builtin_amdgcn_mfma_f32_16x16x32_bf16(fah[rt][0], g0, cA[rt], 0, 0, 0);
                cB[rt] = __builtin_amdgcn_mfma_f32_16x16x32_bf16(fah[rt][1], g1, cB[rt], 0, 0, 0);
            }
        };
        auto FOLD = [&](int j, f32x4 (&cA)[2], f32x4 (&cB)[2]) {
            unsigned invc = 511u - (unsigned)((chunk << 5) + (j << 4) + col);
            #pragma unroll
            for (int rt = 0; rt < 2; ++rt)
                #pragma unroll
                for (int r = 0; r < 4; ++r) {
                    float m = cA[rt][r] + cB[rt][r];           // positive
                    unsigned ki  = (unsigned)(int)m;           // floor, monotone
                    unsigned key = (ki << 9) + invc;           // lshl_add
                    unsigned a = key > v2k[rt][r] ? key : v2k[rt][r];
                    v2k[rt][r] = a < v1k[rt][r] ? a : v1k[rt][r];
                    v1k[rt][r] = key > v1k[rt][r] ? key : v1k[rt][r];
                }
        };

        // 2 tiles per chunk, 2-slot rotation
        f32x4 sA0[2], sB0[2], sA1[2], sB1[2];
        INIT(0, sA0, sB0); STEP(0, sA0, sB0);
        INIT(1, sA1, sB1); STEP(1, sA1, sB1);
        FOLD(0, sA0, sB0);
        FOLD(1, sA1, sB1);

        if (chunk < 15) {
            // write NEXT chunk into the idle buffer; all reads of that buffer
            // completed before the previous barrier (barriers are collective).
            *(u16x8*)((char*)bhi[(chunk + 1) & 1] + w * 1024 + l * 16) = nh;
            *(u16x8*)((char*)blo[(chunk + 1) & 1] + w * 1024 + l * 16) = nl;
            __syncthreads();
        }
    }

    // ---- cross-lane top-2 merge over the 16 cols sharing each row (keys) ----
    #pragma unroll
    for (int off = 1; off <= 8; off <<= 1) {
        #pragma unroll
        for (int rt = 0; rt < 2; ++rt)
            #pragma unroll
            for (int r = 0; r < 4; ++r) {
                unsigned o1 = (unsigned)__shfl_xor((int)v1k[rt][r], off);
                unsigned o2 = (unsigned)__shfl_xor((int)v2k[rt][r], off);
                unsigned lo = min(v1k[rt][r], o1);
                v1k[rt][r]  = max(v1k[rt][r], o1);
                v2k[rt][r]  = max(lo, max(v2k[rt][r], o2));
            }
    }
    if (col == 0) {
        #pragma unroll
        for (int rt = 0; rt < 2; ++rt)
            #pragma unroll
            for (int r = 0; r < 4; ++r) {
                unsigned k1 = v1k[rt][r], k2 = v2k[rt][r];
                int z1 = 511 - (int)(k1 & 0x1FFu);
                int z2 = 511 - (int)(k2 & 0x1FFu);
                // integer gate: gap < 13/256 ~ 0.051 >> split ~1e-3 + quantum 0.0039
                bool need = ((k1 >> 9) - (k2 >> 9)) < 13u;
                top2s[(w << 5) + (rt << 4) + (ksl << 2) + r] = make_int2(z1, need ? z2 : z1);
            }
    }
    __syncthreads();

    // ---- refine: 16 lanes/row, 4 rows/iter (1KB contiguous stores);
    //      f64 delta only when top-2 genuinely close ----
    const int qo = (l & 15) << 2;       // float offset within row
    const int rq = l >> 4;              // row within 4-row group
    double macc = 0.0;
    #pragma unroll
    for (int it = 0; it < 8; ++it) {
        int  rloc = (w << 5) + (it << 2) + rq;      // block-local row 0..127
        int  lrow = lt * 128 + rloc;
        long grow = (long)bh * Lc + lrow;
        int2 zz   = top2s[rloc];
        const float* Ar = Avec + (size_t)rloc * DKc;
        const float* C1 = Bp + (size_t)zz.x * DKc;
        const float* C2 = Bp + (size_t)zz.y * DKc;
        f32x4 va = *reinterpret_cast<const f32x4*>(Ar + qo);
        f32x4 ca = *reinterpret_cast<const f32x4*>(C1 + qo);
        f32x4 cb = *reinterpret_cast<const f32x4*>(C2 + qo);
        double dd = 0.0;                // d1 - d2 = sum (c1-c2)*((c1+c2) - 2v)
        if (zz.x != zz.y) {             // uniform across the row's 16 lanes
            #pragma unroll
            for (int m = 0; m < 4; ++m) {
                double a = (double)ca[m], bb = (double)cb[m], vv = (double)va[m];
                dd = fma(a - bb, (a + bb) - 2.0 * vv, dd);
            }
            dd += __shfl_xor(dd, 1);
            dd += __shfl_xor(dd, 2);
            dd += __shfl_xor(dd, 4);
            dd += __shfl_xor(dd, 8);
        }
        bool second = (dd > 0.0) || (dd == 0.0 && zz.y < zz.x);
        int zsel = second ? zz.y : zz.x;
        f32x4 cs = second ? cb : ca;
        float e = 0.f;
        #pragma unroll
        for (int m = 0; m < 4; ++m) {
            float td = va[m] - cs[m];
            e = fmaf(td, td, e);
        }
        e += __shfl_xor(e, 1);
        e += __shfl_xor(e, 2);
        e += __shfl_xor(e, 4);
        e += __shfl_xor(e, 8);
        *reinterpret_cast<f32x4*>(out_vh + (size_t)grow * DKc + qo) = cs;
        if ((l & 15) == 0) {
            out_z[grow]   = (float)zsel;
            out_err[grow] = e;
            macc += (double)loss_mask[b * Lc + lrow] * (double)e;
        }
    }
    macc += __shfl_xor(macc, 16);
    macc += __shfl_xor(macc, 32);
    if (l == 0) partials[flat * 4 + w] = (float)macc;
}

// ---------------- finalize ----------------
__global__ __launch_bounds__(256) void finalize_kernel(
        const float* __restrict__ partials, int n,
        float* __restrict__ out_lcommit, float* __restrict__ out_lcode) {
    __shared__ double sh[256];
    double a = 0.0;
    for (int i = threadIdx.x; i < n; i += 256) a += (double)partials[i];
    sh[threadIdx.x] = a;
    __syncthreads();
    for (int s = 128; s; s >>= 1) {
        if (threadIdx.x < s) sh[threadIdx.x] += sh[threadIdx.x + s];
        __syncthreads();
    }
    if (threadIdx.x == 0) {
        double lc = sh[0] / (double)(Bc * Lc);
        *out_lcommit = (float)lc;
        *out_lcode   = 0.0f;
    }
}

extern "C" void kernel_launch(void* const* d_in, const int* in_sizes, int n_in,
                              void* d_out, int out_size, void* d_ws, size_t ws_size,
                              hipStream_t stream) {
    const float* vecs      = (const float*)d_in[0];
    const float* c_sum     = (const float*)d_in[1];
    const float* c_count   = (const float*)d_in[2];
    const float* loss_mask = (const float*)d_in[3];
    (void)in_sizes; (void)n_in; (void)out_size; (void)ws_size;

    char* ws = (char*)d_ws;
    float*          c        = (float*)(ws + WS_C_OFF);
    float*          c2       = (float*)(ws + WS_C2_OFF);
    unsigned short* cbh      = (unsigned short*)(ws + WS_CBH_OFF);
    unsigned short* cbl      = (unsigned short*)(ws + WS_CBL_OFF);
    float*          partials = (float*)(ws + WS_PART_OFF);

    float* out = (float*)d_out;
    float* out_vh      = out;                                   // B*H*L*DK
    float* out_z       = out + (size_t)Bc * Hc * Lc * DKc;      // B*H*L
    float* out_lcommit = out_z + (size_t)Bc * Hc * Lc;          // 1
    float* out_lcode   = out_lcommit + 1;                       // 1
    float* out_err     = out_lcode + 1;                         // B*H*L

    prep_kernel<<<(Hc * Sc * 64) / 256, 256, 0, stream>>>(c_sum, c_count, c, c2, cbh, cbl);

    vq_mfma_kernel<<<2048, 256, 0, stream>>>(vecs, c, c2, cbh, cbl, loss_mask,
                                             out_vh, out_z, out_err, partials);

    finalize_kernel<<<1, 256, 0, stream>>>(partials, NPART, out_lcommit, out_lcode);
}